// Round 4
// baseline (601.367 us; speedup 1.0000x reference)
//
#include <hip/hip_runtime.h>

// SRU++ fused pipeline for MI355X (gfx950).
// Stages: x->bf16, W->bf16(transposed), QKV GEMM (MFMA), V transpose,
// flash attention (online softmax) fused with mixed=alpha*F+Q, U GEMM,
// sequential SRU recurrence.
// B=8, L=2048, D=1024, A=256. All GEMMs bf16 MFMA 16x16x32, fp32 accum.

typedef __attribute__((ext_vector_type(4))) float f32x4;
typedef __attribute__((ext_vector_type(8))) short bf16x8;
typedef __attribute__((ext_vector_type(8))) unsigned short u16x8;

__device__ __forceinline__ float b2f(unsigned short u) {
  union { unsigned int i; float f; } v; v.i = ((unsigned int)u) << 16; return v.f;
}
__device__ __forceinline__ unsigned short f2b(float f) {
  union { float f; unsigned int i; } v; v.f = f;
  unsigned int r = v.i + 0x7FFFu + ((v.i >> 16) & 1u);
  return (unsigned short)(r >> 16);
}

typedef __attribute__((address_space(3))) unsigned int lds_u32;
typedef __attribute__((address_space(1))) const unsigned int glb_u32;
__device__ __forceinline__ void gld_lds16(const void* g, void* l) {
  __builtin_amdgcn_global_load_lds((glb_u32*)g, (lds_u32*)l, 16, 0, 0);
}

// ---------------- conversions ----------------
__global__ __launch_bounds__(256) void k_conv_x(const float* __restrict__ x,
                                                unsigned short* __restrict__ xb) {
  size_t i = ((size_t)blockIdx.x * 256 + threadIdx.x) * 8;
  float4 a = *(const float4*)(x + i);
  float4 b = *(const float4*)(x + i + 4);
  u16x8 o;
  o[0] = f2b(a.x); o[1] = f2b(a.y); o[2] = f2b(a.z); o[3] = f2b(a.w);
  o[4] = f2b(b.x); o[5] = f2b(b.y); o[6] = f2b(b.z); o[7] = f2b(b.w);
  *(u16x8*)(xb + i) = o;
}

// wqkvT[n][k] = {Wq|Wk|Wv}[k][n%256]  (768x1024); wuT[n][k] = Wu[k][n] (3072x256)
__global__ __launch_bounds__(256) void k_conv_w(const float* __restrict__ Wq,
                                                const float* __restrict__ Wk,
                                                const float* __restrict__ Wv,
                                                const float* __restrict__ Wu,
                                                unsigned short* __restrict__ wqkvT,
                                                unsigned short* __restrict__ wuT) {
  int id = blockIdx.x * 256 + threadIdx.x;
  if (id < 768 * 1024) {
    int n = id >> 10, k = id & 1023;
    float v;
    if (n < 256)      v = Wq[k * 256 + n];
    else if (n < 512) v = Wk[k * 256 + (n - 256)];
    else              v = Wv[k * 256 + (n - 512)];
    wqkvT[id] = f2b(v);
  } else {
    int id2 = id - 768 * 1024;
    int n = id2 >> 8, k = id2 & 255;
    wuT[id2] = f2b(Wu[k * 3072 + n]);
  }
}

// ---------------- GEMM: C(MxN) = A(MxK) * B^T-stored(NxK), all bf16, m97 structure ----
__global__ __launch_bounds__(256) void k_gemm_bt(const unsigned short* __restrict__ A,
                                                 const unsigned short* __restrict__ B,
                                                 unsigned short* __restrict__ C,
                                                 int M, int N, int K) {
  __shared__ unsigned short As[128 * 32];
  __shared__ unsigned short Bs[128 * 32];
  const int tid = threadIdx.x;
  const int lane = tid & 63, wave = tid >> 6;
  const int m0 = blockIdx.y * 128, n0 = blockIdx.x * 128;
  const int wm = (wave >> 1) * 64, wn = (wave & 1) * 64;
  const int la = lane & 15, lg = lane >> 4;
  f32x4 acc[4][4] = {};
  const int r0 = tid >> 2;          // tile row this thread stages
  const int kk0 = (tid & 3) * 8;    // k offset within tile
  const unsigned short* Ag = A + (size_t)(m0 + r0) * K + kk0;
  const unsigned short* Bg = B + (size_t)(n0 + r0) * K + kk0;
  unsigned short* Al = As + tid * 8;
  unsigned short* Bl = Bs + tid * 8;

  for (int kt = 0; kt < K; kt += 32) {
    gld_lds16(Ag + kt, Al);
    gld_lds16(Ag + kt + (size_t)64 * K, Al + 2048);
    gld_lds16(Bg + kt, Bl);
    gld_lds16(Bg + kt + (size_t)64 * K, Bl + 2048);
    __syncthreads();
    bf16x8 af[4], bfr[4];
#pragma unroll
    for (int mt = 0; mt < 4; ++mt) af[mt]  = *(const bf16x8*)&As[(wm + mt * 16 + la) * 32 + lg * 8];
#pragma unroll
    for (int nt = 0; nt < 4; ++nt) bfr[nt] = *(const bf16x8*)&Bs[(wn + nt * 16 + la) * 32 + lg * 8];
#pragma unroll
    for (int mt = 0; mt < 4; ++mt)
#pragma unroll
      for (int nt = 0; nt < 4; ++nt)
        acc[mt][nt] = __builtin_amdgcn_mfma_f32_16x16x32_bf16(af[mt], bfr[nt], acc[mt][nt], 0, 0, 0);
    __syncthreads();
  }
#pragma unroll
  for (int mt = 0; mt < 4; ++mt)
#pragma unroll
    for (int nt = 0; nt < 4; ++nt)
#pragma unroll
      for (int i = 0; i < 4; ++i) {
        int row = m0 + wm + mt * 16 + lg * 4 + i;
        int col = n0 + wn + nt * 16 + la;
        C[(size_t)row * N + col] = f2b(acc[mt][nt][i]);
      }
}

// ---------------- V transpose: vt[b][n][l] = qkv[b*2048+l][512+n] ----------------
__global__ __launch_bounds__(256) void k_transpose_v(const unsigned short* __restrict__ qkv,
                                                     unsigned short* __restrict__ vt) {
  __shared__ unsigned short tile[32][33];
  int b = blockIdx.z;
  int l0 = blockIdx.x * 32, n0 = blockIdx.y * 32;
  int tx = threadIdx.x, ty = threadIdx.y;  // 32 x 8
#pragma unroll
  for (int i = 0; i < 4; ++i) {
    int l = l0 + ty + i * 8;
    tile[ty + i * 8][tx] = qkv[(size_t)(b * 2048 + l) * 768 + 512 + n0 + tx];
  }
  __syncthreads();
#pragma unroll
  for (int i = 0; i < 4; ++i) {
    int n = n0 + ty + i * 8;
    vt[(size_t)(b * 256 + n) * 2048 + l0 + tx] = tile[tx][ty + i * 8];
  }
}

// ---------------- flash attention + mixed = alpha*F + Q ----------------
// grid (32 qtiles, 8 batches), 256 threads = 4 waves, each wave 16 q-rows.
__global__ __launch_bounds__(256) void k_attn(const unsigned short* __restrict__ qkv,
                                              const unsigned short* __restrict__ vt,
                                              unsigned short* __restrict__ mixed,
                                              const float* __restrict__ alpha_p) {
  __shared__ unsigned short Ks[64][264];     // keys x dims (pad 8)
  __shared__ unsigned short Vs[256][72];     // dims x keys (pad 8)
  __shared__ unsigned short Ps[4][16][72];   // per-wave P: qrow x keys (pad 8)
  const int tid = threadIdx.x;
  const int lane = tid & 63, wave = tid >> 6;
  const int b = blockIdx.y;
  const int qw = blockIdx.x * 64 + wave * 16;
  const int la = lane & 15, lg = lane >> 4;
  const float alpha = *alpha_p;
  const float scale = 0.0625f;  // 1/sqrt(256)

  bf16x8 aq[8];
  {
    const unsigned short* qrow = qkv + (size_t)(b * 2048 + qw + la) * 768;
#pragma unroll
    for (int ks = 0; ks < 8; ++ks) aq[ks] = *(const bf16x8*)(qrow + ks * 32 + lg * 8);
  }
  f32x4 acc[16] = {};
  float mrun[4] = {-1e30f, -1e30f, -1e30f, -1e30f};
  float lrun[4] = {0.f, 0.f, 0.f, 0.f};

  for (int kc = 0; kc < 2048; kc += 64) {
    {  // stage K chunk (64x256) and V chunk (256x64, dim-major)
      const unsigned short* kg = qkv + (size_t)(b * 2048 + kc) * 768 + 256;
#pragma unroll
      for (int i = 0; i < 8; ++i) {
        int chunk = i * 256 + tid;             // 2048 chunks of 16B
        int r = chunk >> 5, ci = chunk & 31;
        *(u16x8*)&Ks[r][ci * 8] = *(const u16x8*)(kg + (size_t)r * 768 + ci * 8);
      }
      const unsigned short* vg = vt + (size_t)(b * 256) * 2048 + kc;
#pragma unroll
      for (int i = 0; i < 8; ++i) {
        int chunk = i * 256 + tid;
        int n = chunk >> 3, ci = chunk & 7;
        *(u16x8*)&Vs[n][ci * 8] = *(const u16x8*)(vg + (size_t)n * 2048 + ci * 8);
      }
    }
    __syncthreads();
    // S = Q K^T  (16 rows x 64 keys), fp32
    f32x4 s[4] = {};
#pragma unroll
    for (int ks = 0; ks < 8; ++ks)
#pragma unroll
      for (int nt = 0; nt < 4; ++nt) {
        bf16x8 bk = *(const bf16x8*)&Ks[nt * 16 + la][ks * 32 + lg * 8];
        s[nt] = __builtin_amdgcn_mfma_f32_16x16x32_bf16(aq[ks], bk, s[nt], 0, 0, 0);
      }
    // online softmax for this 64-key chunk
    float sc_old[4], psum[4];
#pragma unroll
    for (int i = 0; i < 4; ++i) {
      float v = fmaxf(fmaxf(s[0][i], s[1][i]), fmaxf(s[2][i], s[3][i]));
#pragma unroll
      for (int off = 1; off < 16; off <<= 1) v = fmaxf(v, __shfl_xor(v, off, 64));
      v *= scale;
      float mn = fmaxf(mrun[i], v);
      sc_old[i] = __expf(mrun[i] - mn);
      mrun[i] = mn;
      psum[i] = 0.f;
    }
    float pv[4][4];
#pragma unroll
    for (int nt = 0; nt < 4; ++nt)
#pragma unroll
      for (int i = 0; i < 4; ++i) {
        float p = __expf(s[nt][i] * scale - mrun[i]);
        pv[nt][i] = p;
        psum[i] += p;
      }
#pragma unroll
    for (int i = 0; i < 4; ++i) {
      float v = psum[i];
#pragma unroll
      for (int off = 1; off < 16; off <<= 1) v += __shfl_xor(v, off, 64);
      lrun[i] = lrun[i] * sc_old[i] + v;
    }
#pragma unroll
    for (int on = 0; on < 16; ++on)
#pragma unroll
      for (int i = 0; i < 4; ++i) acc[on][i] *= sc_old[i];
    // P: C-layout -> LDS -> A-layout
#pragma unroll
    for (int nt = 0; nt < 4; ++nt)
#pragma unroll
      for (int i = 0; i < 4; ++i)
        Ps[wave][lg * 4 + i][nt * 16 + la] = f2b(pv[nt][i]);
    bf16x8 pa0 = *(const bf16x8*)&Ps[wave][la][lg * 8];
    bf16x8 pa1 = *(const bf16x8*)&Ps[wave][la][32 + lg * 8];
#pragma unroll
    for (int on = 0; on < 16; ++on) {
      bf16x8 bv0 = *(const bf16x8*)&Vs[on * 16 + la][lg * 8];
      bf16x8 bv1 = *(const bf16x8*)&Vs[on * 16 + la][32 + lg * 8];
      acc[on] = __builtin_amdgcn_mfma_f32_16x16x32_bf16(pa0, bv0, acc[on], 0, 0, 0);
      acc[on] = __builtin_amdgcn_mfma_f32_16x16x32_bf16(pa1, bv1, acc[on], 0, 0, 0);
    }
    __syncthreads();
  }
  float invl[4];
#pragma unroll
  for (int i = 0; i < 4; ++i) invl[i] = 1.f / lrun[i];
#pragma unroll
  for (int on = 0; on < 16; ++on)
#pragma unroll
    for (int i = 0; i < 4; ++i) {
      int row = b * 2048 + qw + lg * 4 + i;
      int col = on * 16 + la;
      float fa = acc[on][i] * invl[i];
      float qv = b2f(qkv[(size_t)row * 768 + col]);
      mixed[(size_t)row * 256 + col] = f2b(alpha * fa + qv);
    }
}

// ---------------- SRU recurrence ----------------
// 8192 chains spread as 128 blocks x 64 threads (128 CUs for BW delivery).
// Software prefetch depth PF=8, all buffer indices compile-time (rule #20).
__global__ __launch_bounds__(64) void k_sru(const unsigned short* __restrict__ U,
                                            const float* __restrict__ x,
                                            const float* __restrict__ vf,
                                            const float* __restrict__ vr,
                                            const float* __restrict__ bfv,
                                            const float* __restrict__ brv,
                                            float* __restrict__ out) {
  constexpr int PF = 8;
  int idx = blockIdx.x * 64 + threadIdx.x;  // (b,d) chain, 8192 total
  int b = idx >> 10, d = idx & 1023;
  const unsigned short* Ub = U + (size_t)b * 2048 * 3072 + d;
  const float* xb = x + (size_t)b * 2048 * 1024 + d;
  float* ob = out + (size_t)b * 2048 * 1024 + d;
  float c = 0.f;
  float vfd = vf[d], vrd = vr[d], bfd = bfv[d], brd = brv[d];

  float buf_uf[PF], buf_ur[PF], buf_uh[PF], buf_x[PF];
#pragma unroll
  for (int j = 0; j < PF; ++j) {
    buf_uf[j] = b2f(Ub[(size_t)j * 3072]);
    buf_ur[j] = b2f(Ub[(size_t)j * 3072 + 1024]);
    buf_uh[j] = b2f(Ub[(size_t)j * 3072 + 2048]);
    buf_x[j]  = xb[(size_t)j * 1024];
  }
  for (int tc = 0; tc < 2048; tc += PF) {
    float n_uf[PF], n_ur[PF], n_uh[PF], n_x[PF];
#pragma unroll
    for (int j = 0; j < PF; ++j) {
      int t = tc + PF + j; t = t < 2047 ? t : 2047;  // clamped prefetch (tail-safe)
      n_uf[j] = b2f(Ub[(size_t)t * 3072]);
      n_ur[j] = b2f(Ub[(size_t)t * 3072 + 1024]);
      n_uh[j] = b2f(Ub[(size_t)t * 3072 + 2048]);
      n_x[j]  = xb[(size_t)t * 1024];
    }
#pragma unroll
    for (int j = 0; j < PF; ++j) {
      float f = 1.f / (1.f + __expf(-(buf_uf[j] + vfd * c + bfd)));
      float cn = f * (c - buf_uh[j]) + buf_uh[j];
      float r = 1.f / (1.f + __expf(-(buf_ur[j] + vrd * c + brd)));
      ob[(size_t)(tc + j) * 1024] = r * (cn - buf_x[j]) + buf_x[j];
      c = cn;
    }
#pragma unroll
    for (int j = 0; j < PF; ++j) {
      buf_uf[j] = n_uf[j]; buf_ur[j] = n_ur[j];
      buf_uh[j] = n_uh[j]; buf_x[j]  = n_x[j];
    }
  }
}

extern "C" void kernel_launch(void* const* d_in, const int* in_sizes, int n_in,
                              void* d_out, int out_size, void* d_ws, size_t ws_size,
                              hipStream_t stream) {
  const float* x     = (const float*)d_in[0];
  const float* Wq    = (const float*)d_in[1];
  const float* Wk    = (const float*)d_in[2];
  const float* Wv    = (const float*)d_in[3];
  const float* Wu    = (const float*)d_in[4];
  const float* vf    = (const float*)d_in[5];
  const float* vr    = (const float*)d_in[6];
  const float* bf_   = (const float*)d_in[7];
  const float* br_   = (const float*)d_in[8];
  const float* alpha = (const float*)d_in[9];

  char* ws = (char*)d_ws;
  // workspace layout (bytes), total ~171 MB
  unsigned short* xb     = (unsigned short*)(ws);               // 33,554,432
  unsigned short* wqkvT  = (unsigned short*)(ws + 33554432);    //  1,572,864
  unsigned short* wuT    = (unsigned short*)(ws + 35127296);    //  1,572,864
  unsigned short* qkv    = (unsigned short*)(ws + 36700160);    // 25,165,824
  unsigned short* vt     = (unsigned short*)(ws + 61865984);    //  8,388,608
  unsigned short* mixedb = (unsigned short*)(ws + 70254592);    //  8,388,608
  unsigned short* Ub     = (unsigned short*)(ws + 78643200);    // 100,663,296
  float* out = (float*)d_out;

  k_conv_x<<<8192, 256, 0, stream>>>(x, xb);
  k_conv_w<<<6144, 256, 0, stream>>>(Wq, Wk, Wv, Wu, wqkvT, wuT);
  k_gemm_bt<<<dim3(6, 128), 256, 0, stream>>>(xb, wqkvT, qkv, 16384, 768, 1024);
  k_transpose_v<<<dim3(64, 8, 8), dim3(32, 8), 0, stream>>>(qkv, vt);
  k_attn<<<dim3(32, 8), 256, 0, stream>>>(qkv, vt, mixedb, alpha);
  k_gemm_bt<<<dim3(24, 128), 256, 0, stream>>>(mixedb, wuT, Ub, 16384, 3072, 256);
  k_sru<<<128, 64, 0, stream>>>(Ub, x, vf, vr, bf_, br_, out);
}

// Round 5
// 571.758 us; speedup vs baseline: 1.0518x; 1.0518x over previous
//
#include <hip/hip_runtime.h>

// SRU++ fused pipeline for MI355X (gfx950).
// Stages: x->bf16, W->bf16(transposed), QKV GEMM (MFMA), V transpose,
// flash attention (online softmax) fused with mixed=alpha*F+Q, U GEMM
// (writes blocked U layout), SRU recurrence with asm-counted prefetch.
// B=8, L=2048, D=1024, A=256. All GEMMs bf16 MFMA 16x16x32, fp32 accum.

typedef __attribute__((ext_vector_type(4))) float f32x4;
typedef __attribute__((ext_vector_type(8))) short bf16x8;
typedef __attribute__((ext_vector_type(8))) unsigned short u16x8;

__device__ __forceinline__ float b2f(unsigned short u) {
  union { unsigned int i; float f; } v; v.i = ((unsigned int)u) << 16; return v.f;
}
__device__ __forceinline__ unsigned short f2b(float f) {
  union { float f; unsigned int i; } v; v.f = f;
  unsigned int r = v.i + 0x7FFFu + ((v.i >> 16) & 1u);
  return (unsigned short)(r >> 16);
}

typedef __attribute__((address_space(3))) unsigned int lds_u32;
typedef __attribute__((address_space(1))) const unsigned int glb_u32;
__device__ __forceinline__ void gld_lds16(const void* g, void* l) {
  __builtin_amdgcn_global_load_lds((glb_u32*)g, (lds_u32*)l, 16, 0, 0);
}

// ---------------- conversions ----------------
__global__ __launch_bounds__(256) void k_conv_x(const float* __restrict__ x,
                                                unsigned short* __restrict__ xb) {
  size_t i = ((size_t)blockIdx.x * 256 + threadIdx.x) * 8;
  float4 a = *(const float4*)(x + i);
  float4 b = *(const float4*)(x + i + 4);
  u16x8 o;
  o[0] = f2b(a.x); o[1] = f2b(a.y); o[2] = f2b(a.z); o[3] = f2b(a.w);
  o[4] = f2b(b.x); o[5] = f2b(b.y); o[6] = f2b(b.z); o[7] = f2b(b.w);
  *(u16x8*)(xb + i) = o;
}

// wqkvT[n][k] = {Wq|Wk|Wv}[k][n%256]  (768x1024); wuT[n][k] = Wu[k][n] (3072x256)
__global__ __launch_bounds__(256) void k_conv_w(const float* __restrict__ Wq,
                                                const float* __restrict__ Wk,
                                                const float* __restrict__ Wv,
                                                const float* __restrict__ Wu,
                                                unsigned short* __restrict__ wqkvT,
                                                unsigned short* __restrict__ wuT) {
  int id = blockIdx.x * 256 + threadIdx.x;
  if (id < 768 * 1024) {
    int n = id >> 10, k = id & 1023;
    float v;
    if (n < 256)      v = Wq[k * 256 + n];
    else if (n < 512) v = Wk[k * 256 + (n - 256)];
    else              v = Wv[k * 256 + (n - 512)];
    wqkvT[id] = f2b(v);
  } else {
    int id2 = id - 768 * 1024;
    int n = id2 >> 8, k = id2 & 255;
    wuT[id2] = f2b(Wu[k * 3072 + n]);
  }
}

// ---------------- GEMM: C(MxN) = A(MxK) * B^T-stored(NxK), all bf16, m97 structure ----
// MODE 0: row-major C.  MODE 1: blocked-U store [b][a][t/8][d][8] for k_sru.
template <int MODE>
__global__ __launch_bounds__(256) void k_gemm_bt(const unsigned short* __restrict__ A,
                                                 const unsigned short* __restrict__ B,
                                                 unsigned short* __restrict__ C,
                                                 int M, int N, int K) {
  __shared__ unsigned short As[128 * 32];
  __shared__ unsigned short Bs[128 * 32];
  const int tid = threadIdx.x;
  const int lane = tid & 63, wave = tid >> 6;
  const int m0 = blockIdx.y * 128, n0 = blockIdx.x * 128;
  const int wm = (wave >> 1) * 64, wn = (wave & 1) * 64;
  const int la = lane & 15, lg = lane >> 4;
  f32x4 acc[4][4] = {};
  const int r0 = tid >> 2;          // tile row this thread stages
  const int kk0 = (tid & 3) * 8;    // k offset within tile
  const unsigned short* Ag = A + (size_t)(m0 + r0) * K + kk0;
  const unsigned short* Bg = B + (size_t)(n0 + r0) * K + kk0;
  unsigned short* Al = As + tid * 8;
  unsigned short* Bl = Bs + tid * 8;

  for (int kt = 0; kt < K; kt += 32) {
    gld_lds16(Ag + kt, Al);
    gld_lds16(Ag + kt + (size_t)64 * K, Al + 2048);
    gld_lds16(Bg + kt, Bl);
    gld_lds16(Bg + kt + (size_t)64 * K, Bl + 2048);
    __syncthreads();
    bf16x8 af[4], bfr[4];
#pragma unroll
    for (int mt = 0; mt < 4; ++mt) af[mt]  = *(const bf16x8*)&As[(wm + mt * 16 + la) * 32 + lg * 8];
#pragma unroll
    for (int nt = 0; nt < 4; ++nt) bfr[nt] = *(const bf16x8*)&Bs[(wn + nt * 16 + la) * 32 + lg * 8];
#pragma unroll
    for (int mt = 0; mt < 4; ++mt)
#pragma unroll
      for (int nt = 0; nt < 4; ++nt)
        acc[mt][nt] = __builtin_amdgcn_mfma_f32_16x16x32_bf16(af[mt], bfr[nt], acc[mt][nt], 0, 0, 0);
    __syncthreads();
  }
#pragma unroll
  for (int mt = 0; mt < 4; ++mt)
#pragma unroll
    for (int nt = 0; nt < 4; ++nt)
#pragma unroll
      for (int i = 0; i < 4; ++i) {
        int row = m0 + wm + mt * 16 + lg * 4 + i;
        int col = n0 + wn + nt * 16 + la;
        if constexpr (MODE == 0) {
          C[(size_t)row * N + col] = f2b(acc[mt][nt][i]);
        } else {
          int bb = row >> 11, t = row & 2047;
          int a = col >> 10, dd = col & 1023;
          size_t off = (((size_t)(bb * 3 + a) * 256 + (t >> 3)) * 1024 + dd) * 8 + (t & 7);
          C[off] = f2b(acc[mt][nt][i]);
        }
      }
}

// ---------------- V transpose: vt[b][n][l] = qkv[b*2048+l][512+n] ----------------
__global__ __launch_bounds__(256) void k_transpose_v(const unsigned short* __restrict__ qkv,
                                                     unsigned short* __restrict__ vt) {
  __shared__ unsigned short tile[32][33];
  int b = blockIdx.z;
  int l0 = blockIdx.x * 32, n0 = blockIdx.y * 32;
  int tx = threadIdx.x, ty = threadIdx.y;  // 32 x 8
#pragma unroll
  for (int i = 0; i < 4; ++i) {
    int l = l0 + ty + i * 8;
    tile[ty + i * 8][tx] = qkv[(size_t)(b * 2048 + l) * 768 + 512 + n0 + tx];
  }
  __syncthreads();
#pragma unroll
  for (int i = 0; i < 4; ++i) {
    int n = n0 + ty + i * 8;
    vt[(size_t)(b * 256 + n) * 2048 + l0 + tx] = tile[tx][ty + i * 8];
  }
}

// ---------------- flash attention + mixed = alpha*F + Q ----------------
// grid (32 qtiles, 8 batches), 256 threads = 4 waves, each wave 16 q-rows.
__global__ __launch_bounds__(256) void k_attn(const unsigned short* __restrict__ qkv,
                                              const unsigned short* __restrict__ vt,
                                              unsigned short* __restrict__ mixed,
                                              const float* __restrict__ alpha_p) {
  __shared__ unsigned short Ks[64][264];     // keys x dims (pad 8)
  __shared__ unsigned short Vs[256][72];     // dims x keys (pad 8)
  __shared__ unsigned short Ps[4][16][72];   // per-wave P: qrow x keys (pad 8)
  const int tid = threadIdx.x;
  const int lane = tid & 63, wave = tid >> 6;
  const int b = blockIdx.y;
  const int qw = blockIdx.x * 64 + wave * 16;
  const int la = lane & 15, lg = lane >> 4;
  const float alpha = *alpha_p;
  const float scale = 0.0625f;  // 1/sqrt(256)

  bf16x8 aq[8];
  {
    const unsigned short* qrow = qkv + (size_t)(b * 2048 + qw + la) * 768;
#pragma unroll
    for (int ks = 0; ks < 8; ++ks) aq[ks] = *(const bf16x8*)(qrow + ks * 32 + lg * 8);
  }
  f32x4 acc[16] = {};
  float mrun[4] = {-1e30f, -1e30f, -1e30f, -1e30f};
  float lrun[4] = {0.f, 0.f, 0.f, 0.f};

  for (int kc = 0; kc < 2048; kc += 64) {
    {  // stage K chunk (64x256) and V chunk (256x64, dim-major)
      const unsigned short* kg = qkv + (size_t)(b * 2048 + kc) * 768 + 256;
#pragma unroll
      for (int i = 0; i < 8; ++i) {
        int chunk = i * 256 + tid;             // 2048 chunks of 16B
        int r = chunk >> 5, ci = chunk & 31;
        *(u16x8*)&Ks[r][ci * 8] = *(const u16x8*)(kg + (size_t)r * 768 + ci * 8);
      }
      const unsigned short* vg = vt + (size_t)(b * 256) * 2048 + kc;
#pragma unroll
      for (int i = 0; i < 8; ++i) {
        int chunk = i * 256 + tid;
        int n = chunk >> 3, ci = chunk & 7;
        *(u16x8*)&Vs[n][ci * 8] = *(const u16x8*)(vg + (size_t)n * 2048 + ci * 8);
      }
    }
    __syncthreads();
    // S = Q K^T  (16 rows x 64 keys), fp32
    f32x4 s[4] = {};
#pragma unroll
    for (int ks = 0; ks < 8; ++ks)
#pragma unroll
      for (int nt = 0; nt < 4; ++nt) {
        bf16x8 bk = *(const bf16x8*)&Ks[nt * 16 + la][ks * 32 + lg * 8];
        s[nt] = __builtin_amdgcn_mfma_f32_16x16x32_bf16(aq[ks], bk, s[nt], 0, 0, 0);
      }
    // online softmax for this 64-key chunk
    float sc_old[4], psum[4];
#pragma unroll
    for (int i = 0; i < 4; ++i) {
      float v = fmaxf(fmaxf(s[0][i], s[1][i]), fmaxf(s[2][i], s[3][i]));
#pragma unroll
      for (int off = 1; off < 16; off <<= 1) v = fmaxf(v, __shfl_xor(v, off, 64));
      v *= scale;
      float mn = fmaxf(mrun[i], v);
      sc_old[i] = __expf(mrun[i] - mn);
      mrun[i] = mn;
      psum[i] = 0.f;
    }
    float pv[4][4];
#pragma unroll
    for (int nt = 0; nt < 4; ++nt)
#pragma unroll
      for (int i = 0; i < 4; ++i) {
        float p = __expf(s[nt][i] * scale - mrun[i]);
        pv[nt][i] = p;
        psum[i] += p;
      }
#pragma unroll
    for (int i = 0; i < 4; ++i) {
      float v = psum[i];
#pragma unroll
      for (int off = 1; off < 16; off <<= 1) v += __shfl_xor(v, off, 64);
      lrun[i] = lrun[i] * sc_old[i] + v;
    }
#pragma unroll
    for (int on = 0; on < 16; ++on)
#pragma unroll
      for (int i = 0; i < 4; ++i) acc[on][i] *= sc_old[i];
    // P: C-layout -> LDS -> A-layout
#pragma unroll
    for (int nt = 0; nt < 4; ++nt)
#pragma unroll
      for (int i = 0; i < 4; ++i)
        Ps[wave][lg * 4 + i][nt * 16 + la] = f2b(pv[nt][i]);
    bf16x8 pa0 = *(const bf16x8*)&Ps[wave][la][lg * 8];
    bf16x8 pa1 = *(const bf16x8*)&Ps[wave][la][32 + lg * 8];
#pragma unroll
    for (int on = 0; on < 16; ++on) {
      bf16x8 bv0 = *(const bf16x8*)&Vs[on * 16 + la][lg * 8];
      bf16x8 bv1 = *(const bf16x8*)&Vs[on * 16 + la][32 + lg * 8];
      acc[on] = __builtin_amdgcn_mfma_f32_16x16x32_bf16(pa0, bv0, acc[on], 0, 0, 0);
      acc[on] = __builtin_amdgcn_mfma_f32_16x16x32_bf16(pa1, bv1, acc[on], 0, 0, 0);
    }
    __syncthreads();
  }
  float invl[4];
#pragma unroll
  for (int i = 0; i < 4; ++i) invl[i] = 1.f / lrun[i];
#pragma unroll
  for (int on = 0; on < 16; ++on)
#pragma unroll
    for (int i = 0; i < 4; ++i) {
      int row = b * 2048 + qw + lg * 4 + i;
      int col = on * 16 + la;
      float fa = acc[on][i] * invl[i];
      float qv = b2f(qkv[(size_t)row * 768 + col]);
      mixed[(size_t)row * 256 + col] = f2b(alpha * fa + qv);
    }
}

// ---------------- SRU recurrence (asm-counted prefetch pipeline) ----------------
// U in blocked layout [b][a][t/8][d][8] bf16 (written by k_gemm_bt<1>).
// Per chunk (8 t-steps): 3x global_load_dwordx4 (U) + 8x global_load_dword (x).
// 4 slots in flight; s_waitcnt vmcnt(33) = loads-only count of 3 younger chunks
// (safe under in-order load retirement regardless of store retirement).
struct SruSlot {
  u16x8 uf, ur, uh;
  float xs[8];
};

__device__ __forceinline__ void sru_issue(SruSlot& s,
                                          const unsigned short* Uf,
                                          const unsigned short* Ur,
                                          const unsigned short* Uh,
                                          const float* xb, int cc) {
  int tt = cc < 255 ? cc : 255;  // clamped tail prefetch (valid addr, unused)
  const unsigned short* pf = Uf + (size_t)tt * 8192;
  const unsigned short* pr = Ur + (size_t)tt * 8192;
  const unsigned short* ph = Uh + (size_t)tt * 8192;
  asm volatile("global_load_dwordx4 %0, %1, off" : "=v"(s.uf) : "v"(pf));
  asm volatile("global_load_dwordx4 %0, %1, off" : "=v"(s.ur) : "v"(pr));
  asm volatile("global_load_dwordx4 %0, %1, off" : "=v"(s.uh) : "v"(ph));
  const float* px = xb + (size_t)tt * 8192;  // 8 steps * 1024
#pragma unroll
  for (int j = 0; j < 8; ++j)
    asm volatile("global_load_dword %0, %1, off" : "=v"(s.xs[j]) : "v"(px + j * 1024));
}

__device__ __forceinline__ void sru_compute(const SruSlot& s, float& c,
                                            float vfd, float vrd, float bfd, float brd,
                                            float* ob, int cc) {
#pragma unroll
  for (int j = 0; j < 8; ++j) {
    float uf = b2f((unsigned short)s.uf[j]);
    float ur = b2f((unsigned short)s.ur[j]);
    float uh = b2f((unsigned short)s.uh[j]);
    float xt = s.xs[j];
    float f = 1.f / (1.f + __expf(-(uf + vfd * c + bfd)));
    float cn = f * (c - uh) + uh;
    float r = 1.f / (1.f + __expf(-(ur + vrd * c + brd)));
    ob[(size_t)(cc * 8 + j) * 1024] = r * (cn - xt) + xt;
    c = cn;
  }
}

#define SRU_WAIT()                                      \
  do {                                                  \
    asm volatile("s_waitcnt vmcnt(33)" ::: "memory");   \
    __builtin_amdgcn_sched_barrier(0);                  \
  } while (0)

__global__ __launch_bounds__(64) void k_sru(const unsigned short* __restrict__ U,
                                            const float* __restrict__ x,
                                            const float* __restrict__ vf,
                                            const float* __restrict__ vr,
                                            const float* __restrict__ bfv,
                                            const float* __restrict__ brv,
                                            float* __restrict__ out) {
  int idx = blockIdx.x * 32 + threadIdx.x;  // 256 blocks x 32 threads = 8192 chains
  int b = idx >> 10, d = idx & 1023;
  const unsigned short* Uf = U + ((size_t)(b * 3 + 0) << 21) + d * 8;
  const unsigned short* Ur = U + ((size_t)(b * 3 + 1) << 21) + d * 8;
  const unsigned short* Uh = U + ((size_t)(b * 3 + 2) << 21) + d * 8;
  const float* xb = x + (size_t)b * 2048 * 1024 + d;
  float* ob = out + (size_t)b * 2048 * 1024 + d;
  float c = 0.f;
  float vfd = vf[d], vrd = vr[d], bfd = bfv[d], brd = brv[d];

  SruSlot s0, s1, s2, s3;
  sru_issue(s0, Uf, Ur, Uh, xb, 0);
  sru_issue(s1, Uf, Ur, Uh, xb, 1);
  sru_issue(s2, Uf, Ur, Uh, xb, 2);
  sru_issue(s3, Uf, Ur, Uh, xb, 3);
  for (int base = 0; base < 256; base += 4) {
    SRU_WAIT(); sru_compute(s0, c, vfd, vrd, bfd, brd, ob, base + 0); sru_issue(s0, Uf, Ur, Uh, xb, base + 4);
    SRU_WAIT(); sru_compute(s1, c, vfd, vrd, bfd, brd, ob, base + 1); sru_issue(s1, Uf, Ur, Uh, xb, base + 5);
    SRU_WAIT(); sru_compute(s2, c, vfd, vrd, bfd, brd, ob, base + 2); sru_issue(s2, Uf, Ur, Uh, xb, base + 6);
    SRU_WAIT(); sru_compute(s3, c, vfd, vrd, bfd, brd, ob, base + 3); sru_issue(s3, Uf, Ur, Uh, xb, base + 7);
  }
}

extern "C" void kernel_launch(void* const* d_in, const int* in_sizes, int n_in,
                              void* d_out, int out_size, void* d_ws, size_t ws_size,
                              hipStream_t stream) {
  const float* x     = (const float*)d_in[0];
  const float* Wq    = (const float*)d_in[1];
  const float* Wk    = (const float*)d_in[2];
  const float* Wv    = (const float*)d_in[3];
  const float* Wu    = (const float*)d_in[4];
  const float* vf    = (const float*)d_in[5];
  const float* vr    = (const float*)d_in[6];
  const float* bf_   = (const float*)d_in[7];
  const float* br_   = (const float*)d_in[8];
  const float* alpha = (const float*)d_in[9];

  char* ws = (char*)d_ws;
  // workspace layout (bytes), total ~171 MB
  unsigned short* xb     = (unsigned short*)(ws);               // 33,554,432
  unsigned short* wqkvT  = (unsigned short*)(ws + 33554432);    //  1,572,864
  unsigned short* wuT    = (unsigned short*)(ws + 35127296);    //  1,572,864
  unsigned short* qkv    = (unsigned short*)(ws + 36700160);    // 25,165,824
  unsigned short* vt     = (unsigned short*)(ws + 61865984);    //  8,388,608
  unsigned short* mixedb = (unsigned short*)(ws + 70254592);    //  8,388,608
  unsigned short* Ub     = (unsigned short*)(ws + 78643200);    // 100,663,296 (blocked)
  float* out = (float*)d_out;

  k_conv_x<<<8192, 256, 0, stream>>>(x, xb);
  k_conv_w<<<6144, 256, 0, stream>>>(Wq, Wk, Wv, Wu, wqkvT, wuT);
  k_gemm_bt<0><<<dim3(6, 128), 256, 0, stream>>>(xb, wqkvT, qkv, 16384, 768, 1024);
  k_transpose_v<<<dim3(64, 8, 8), dim3(32, 8), 0, stream>>>(qkv, vt);
  k_attn<<<dim3(32, 8), 256, 0, stream>>>(qkv, vt, mixedb, alpha);
  k_gemm_bt<1><<<dim3(24, 128), 256, 0, stream>>>(mixedb, wuT, Ub, 16384, 3072, 256);
  k_sru<<<256, 32, 0, stream>>>(Ub, x, vf, vr, bf_, br_, out);
}